// Round 1
// baseline (431.389 us; speedup 1.0000x reference)
//
#include <hip/hip_runtime.h>

// VQ codebook: z_e [32,64,64,64] f32 (B,C,W,H), emb [1024,64] f32.
// Outputs concat: quantized [32,64,64,64] f32, indices [131072] (as f32), vq_loss [1] f32.

#define CDIM   64
#define KCODES 1024
#define NPTS   131072      // 32*64*64
#define WH     4096        // 64*64
#define CWH    262144      // 64*4096
#define NBLK   512         // NPTS / 256

// Kernel 0: E[k] = ||emb_k||^2
__global__ __launch_bounds__(256) void vq_esq(const float* __restrict__ emb,
                                              float* __restrict__ E) {
    int k = blockIdx.x * 256 + threadIdx.x;
    if (k >= KCODES) return;
    const float4* e4 = (const float4*)(emb + k * CDIM);
    float s = 0.f;
#pragma unroll
    for (int i = 0; i < CDIM / 4; ++i) {
        float4 v = e4[i];
        s = fmaf(v.x, v.x, s);
        s = fmaf(v.y, v.y, s);
        s = fmaf(v.z, v.z, s);
        s = fmaf(v.w, v.w, s);
    }
    E[k] = s;
}

// Kernel 1: per-point argmin over 1024 codes + write quantized/indices + loss partials.
__global__ __launch_bounds__(256) void vq_main(const float* __restrict__ z_e,
                                               const float* __restrict__ emb,
                                               const float* __restrict__ E,
                                               float* __restrict__ out_q,
                                               float* __restrict__ out_idx,
                                               float* __restrict__ partials) {
    const int tid = threadIdx.x;
    const int n   = blockIdx.x * 256 + tid;
    const int b   = n >> 12;       // n / 4096
    const int wh  = n & 4095;

    // Load this point's 64 channels into registers. Coalesced: for fixed c,
    // consecutive lanes read consecutive wh.
    const float* zp = z_e + (size_t)b * CWH + wh;
    float z[CDIM];
#pragma unroll
    for (int c = 0; c < CDIM; ++c) z[c] = zp[c * WH];

    // Argmin over codes. emb row address is wave-uniform -> scalar loads.
    float best  = 1e30f;
    int   bestk = 0;
    for (int k = 0; k < KCODES; ++k) {
        const float* er = emb + k * CDIM;
        float d0 = 0.f, d1 = 0.f, d2 = 0.f, d3 = 0.f;
#pragma unroll
        for (int c = 0; c < CDIM; c += 4) {
            d0 = fmaf(z[c + 0], er[c + 0], d0);
            d1 = fmaf(z[c + 1], er[c + 1], d1);
            d2 = fmaf(z[c + 2], er[c + 2], d2);
            d3 = fmaf(z[c + 3], er[c + 3], d3);
        }
        float dot   = (d0 + d1) + (d2 + d3);
        float score = fmaf(-2.0f, dot, E[k]);   // ||e||^2 - 2 z.e  (+||z||^2 const)
        if (score < best) { best = score; bestk = k; }   // strict <: first-min tie-break
    }

    // Gather winning code, write quantized (coalesced per-c across lanes),
    // accumulate squared diff for loss.
    const float* eb = emb + bestk * CDIM;
    float* qp = out_q + (size_t)b * CWH + wh;
    float lsum = 0.f;
#pragma unroll
    for (int c = 0; c < CDIM; ++c) {
        float v = eb[c];
        qp[c * WH] = v;
        float d = v - z[c];
        lsum = fmaf(d, d, lsum);
    }
    out_idx[n] = (float)bestk;

    // Deterministic block reduction of loss partial.
    __shared__ float red[256];
    red[tid] = lsum;
    __syncthreads();
    for (int s = 128; s > 0; s >>= 1) {
        if (tid < s) red[tid] += red[tid + s];
        __syncthreads();
    }
    if (tid == 0) partials[blockIdx.x] = red[0];
}

// Kernel 2: final deterministic reduction of 512 partials -> loss.
__global__ __launch_bounds__(512) void vq_loss_fin(const float* __restrict__ partials,
                                                   float* __restrict__ loss) {
    __shared__ float red[NBLK];
    int t = threadIdx.x;
    red[t] = partials[t];
    __syncthreads();
    for (int s = NBLK / 2; s > 0; s >>= 1) {
        if (t < s) red[t] += red[t + s];
        __syncthreads();
    }
    if (t == 0) loss[0] = red[0] * (1.25f / 8388608.0f);  // (1+BETA)*mean, B*C*W*H elems
}

extern "C" void kernel_launch(void* const* d_in, const int* in_sizes, int n_in,
                              void* d_out, int out_size, void* d_ws, size_t ws_size,
                              hipStream_t stream) {
    const float* z_e = (const float*)d_in[0];
    const float* emb = (const float*)d_in[1];

    float* out      = (float*)d_out;
    float* out_q    = out;                       // 8388608 elems
    float* out_idx  = out + 8388608;             // 131072 elems (float-encoded ints)
    float* out_loss = out + 8388608 + 131072;    // 1 elem

    float* E        = (float*)d_ws;              // 1024 floats
    float* partials = E + KCODES;                // 512 floats

    vq_esq<<<KCODES / 256, 256, 0, stream>>>(emb, E);
    vq_main<<<NBLK, 256, 0, stream>>>(z_e, emb, E, out_q, out_idx, partials);
    vq_loss_fin<<<1, NBLK, 0, stream>>>(partials, out_loss);
}